// Round 3
// baseline (249.255 us; speedup 1.0000x reference)
//
#include <hip/hip_runtime.h>
#include <stdint.h>

// Problem constants (fixed by reference setup_inputs)
constexpr int B_ = 8, N_ = 2048, M_ = 2048, K_ = 64;
constexpr int QROWS = 512;  // M rows staged in LDS per phase (4 phases)

// Workspace layout (float offsets).
constexpr int WS_ACC = 0;       // [1]       global fp32 accumulator
constexpr int WS_CNT = 8;       // [1]       int done-counter for final reduce
constexpr int WS_MU  = 16;      // [B*9]     per-batch mean of targets
constexpr int WS_S   = 256;     // [B*81]    S = C + C^T (C = pinv(cov))
constexpr int WS_QB  = 4096;    // [B*N]     qb = 0.5 b^T S b
constexpr int WS_QA  = 20480;   // [B*M]     qa = 0.5 a^T S a
constexpr int WS_U9  = 36864;   // [B*M*9]   u = S a (9 floats/row)

// ---------------------------------------------------------------------------
// Kernel 1 (fused): per-batch raw moments -> mu, cov -> S = C + C^T with
// C = pinv(cov) = inv(cov^T cov) cov^T via fp64 Gauss-Jordan in LDS.
// Grid: B_ blocks x 256 threads; each thread reduces 8 rows.
// ---------------------------------------------------------------------------
__global__ __launch_bounds__(256) void stats_pinv_kernel(const float* __restrict__ targets,
                                                         float* __restrict__ ws)
{
    const int b = blockIdx.x, tid = threadIdx.x;
    float s[9], cc[45];
#pragma unroll
    for (int d = 0; d < 9; ++d) s[d] = 0.f;
#pragma unroll
    for (int i = 0; i < 45; ++i) cc[i] = 0.f;

    const float* T = targets + (size_t)b * M_ * 9;
#pragma unroll
    for (int r = 0; r < 8; ++r) {
        const float* row = T + (r * 256 + tid) * 9;
        float y[9];
#pragma unroll
        for (int d = 0; d < 9; ++d) { y[d] = row[d]; s[d] += y[d]; }
        int idx = 0;
#pragma unroll
        for (int i = 0; i < 9; ++i)
#pragma unroll
            for (int j = i; j < 9; ++j) { cc[idx] = fmaf(y[i], y[j], cc[idx]); ++idx; }
    }
#pragma unroll
    for (int o = 32; o; o >>= 1) {
#pragma unroll
        for (int d = 0; d < 9; ++d) s[d] += __shfl_xor(s[d], o, 64);
#pragma unroll
        for (int i = 0; i < 45; ++i) cc[i] += __shfl_xor(cc[i], o, 64);
    }
    __shared__ float red[4][54];
    const int wave = tid >> 6, lane = tid & 63;
    if (lane == 0) {
#pragma unroll
        for (int d = 0; d < 9; ++d) red[wave][d] = s[d];
#pragma unroll
        for (int i = 0; i < 45; ++i) red[wave][9 + i] = cc[i];
    }
    __syncthreads();
    if (tid < 54) red[0][tid] = red[0][tid] + red[1][tid] + red[2][tid] + red[3][tid];
    __syncthreads();

    __shared__ double As[81], G[81], Inv[81], Cm[81], fcol[9], smu[9];
    if (tid < 9) {
        const double m = (double)red[0][tid] / M_;
        smu[tid] = m;
        ws[WS_MU + b * 9 + tid] = (float)m;
    }
    __syncthreads();
    if (tid < 81) {  // cov = Sum(yy^T) - M mu mu^T
        const int i = tid / 9, j = tid % 9;
        const int ii = i < j ? i : j, jj = i < j ? j : i;
        const int tri = ii * 9 - ii * (ii - 1) / 2 + (jj - ii);
        As[tid] = (double)red[0][9 + tri] - (double)M_ * smu[i] * smu[j];
    }
    __syncthreads();
    if (tid < 81) {
        const int i = tid / 9, j = tid % 9;
        double sv = 0.0;
#pragma unroll
        for (int k = 0; k < 9; ++k) sv += As[k * 9 + i] * As[k * 9 + j];  // A^T A
        G[tid] = sv;
        Inv[tid] = (i == j) ? 1.0 : 0.0;
    }
    __syncthreads();

    for (int col = 0; col < 9; ++col) {
        const double p = G[col * 9 + col];  // all read before any write
        __syncthreads();
        if (tid < 9) {
            G[col * 9 + tid] /= p;
            Inv[col * 9 + tid] /= p;
        }
        __syncthreads();
        if (tid < 9 && tid != col) fcol[tid] = G[tid * 9 + col];
        __syncthreads();
        if (tid < 81) {
            const int r = tid / 9, j = tid % 9;
            if (r != col) {
                const double f = fcol[r];
                G[tid]   -= f * G[col * 9 + j];
                Inv[tid] -= f * Inv[col * 9 + j];
            }
        }
        __syncthreads();
    }

    if (tid < 81) {  // C = inv(A^T A) A^T
        const int i = tid / 9, j = tid % 9;
        double sv = 0.0;
#pragma unroll
        for (int k = 0; k < 9; ++k) sv += Inv[i * 9 + k] * As[j * 9 + k];
        Cm[tid] = sv;
    }
    __syncthreads();
    if (tid < 81) {
        const int i = tid / 9, j = tid % 9;
        ws[WS_S + b * 81 + tid] = (float)(Cm[i * 9 + j] + Cm[j * 9 + i]);  // S = C + C^T
    }
}

// ---------------------------------------------------------------------------
// Kernel 2: U9 rows (u = S a), QA (0.5 a^T S a), QB (0.5 b^T S b); zero ACC/CNT
// ---------------------------------------------------------------------------
__global__ __launch_bounds__(256) void prep_kernel(const float* __restrict__ outputs,
                                                   const float* __restrict__ targets,
                                                   float* __restrict__ ws)
{
    const int gid = blockIdx.x * 256 + threadIdx.x;
    if (gid == 0) {  // ws is re-poisoned before every call
        ws[WS_ACC] = 0.f;
        ((int*)ws)[WS_CNT] = 0;
    }

    if (gid < B_ * M_) {
        const int b = gid >> 11;
        const float* S  = ws + WS_S + b * 81;
        const float* mu = ws + WS_MU + b * 9;
        const float* r  = targets + (size_t)gid * 9;
        float a[9];
#pragma unroll
        for (int d = 0; d < 9; ++d) a[d] = r[d] - mu[d];
        float qa = 0.f;
#pragma unroll
        for (int d = 0; d < 9; ++d) {
            float u = 0.f;
#pragma unroll
            for (int e = 0; e < 9; ++e) u = fmaf(S[d * 9 + e], a[e], u);
            ws[WS_U9 + (size_t)gid * 9 + d] = u;
            qa = fmaf(u, a[d], qa);
        }
        ws[WS_QA + gid] = 0.5f * qa;
    } else if (gid < B_ * (M_ + N_)) {
        const int g2 = gid - B_ * M_;
        const int b = g2 >> 11;
        const float* S = ws + WS_S + b * 81;
        const float* r = outputs + (size_t)g2 * 9;
        float bb[9];
#pragma unroll
        for (int d = 0; d < 9; ++d) bb[d] = r[d];
        float q = 0.f;
#pragma unroll
        for (int d = 0; d < 9; ++d) {
            float v = 0.f;
#pragma unroll
            for (int e = 0; e < 9; ++e) v = fmaf(S[d * 9 + e], bb[e], v);
            q = fmaf(v, bb[d], q);
        }
        ws[WS_QB + g2] = 0.5f * q;
    }
}

// ---------------------------------------------------------------------------
// Kernel 3: sum-of-top-64 per column. 2 columns/wave; M staged in 4 quarters
// of 512 rows (20 KB LDS -> 8 blocks/CU ceiling). Exact selection via
// monotone-uint binary search (bits 31..12) with BALLOT counting: the v_cmp
// is the whole cross-lane reduction (SGPR mask), popcount+sum on the scalar
// pipe, thresholds live in SGPRs -- no shuffle chains in the search loop.
// Last block folds the final mean into d_out (device-scope counter).
// ---------------------------------------------------------------------------
__global__ __launch_bounds__(256, 4) void topk_kernel(const float* __restrict__ outputs,
                                                      float* __restrict__ ws,
                                                      float* __restrict__ out)
{
    __shared__ float sU[QROWS * 9];  // 18432 B
    __shared__ float sQ[QROWS];      //  2048 B
    const int b = blockIdx.y;
    const int tid = threadIdx.x;
    const int wave = tid >> 6, lane = tid & 63;
    const int n0 = blockIdx.x * 8 + wave * 2;  // this wave's two columns

    const float* brow = outputs + ((size_t)b * N_ + n0) * 9;
    float ba[9], bb[9];
#pragma unroll
    for (int d = 0; d < 9; ++d) { ba[d] = brow[d]; bb[d] = brow[9 + d]; }

    unsigned ua[32], ub[32];
#pragma unroll
    for (int ph = 0; ph < 4; ++ph) {
        __syncthreads();  // protect LDS from previous phase's readers
        const float4* src = (const float4*)(ws + WS_U9 + ((size_t)b * M_ + ph * QROWS) * 9);
        float4* dst = (float4*)sU;
#pragma unroll
        for (int i = 0; i < 4; ++i) dst[i * 256 + tid] = src[i * 256 + tid];
        if (tid < 128) dst[1024 + tid] = src[1024 + tid];
        else ((float4*)sQ)[tid - 128] =
            ((const float4*)(ws + WS_QA + (size_t)b * M_ + ph * QROWS))[tid - 128];
        __syncthreads();

#pragma unroll
        for (int j = 0; j < 8; ++j) {
            const float* r = sU + (j * 64 + lane) * 9;
            const float qa = sQ[j * 64 + lane];
            float aa = qa, ab = qa;
#pragma unroll
            for (int d = 0; d < 9; ++d) {
                const float f = r[d];
                aa = fmaf(-f, ba[d], aa);
                ab = fmaf(-f, bb[d], ab);
            }
            const unsigned xa = __float_as_uint(aa);
            const unsigned xb = __float_as_uint(ab);
            ua[ph * 8 + j] = (xa & 0x80000000u) ? ~xa : (xa | 0x80000000u);
            ub[ph * 8 + j] = (xb & 0x80000000u) ? ~xb : (xb | 0x80000000u);
        }
    }

    // Binary search for tau (64th largest), bits 31..12. Invariant after each
    // bit: count(>=cand) >= K > count(>= cand + 2^bit). Truncation leaves tau
    // exact to 2^-11 relative -> final-mean bias < 1e-6 (threshold 3.7e-4).
    unsigned ca = 0u, cb = 0u;
    for (int bit = 31; bit >= 12; --bit) {
        const unsigned ta = ca | (1u << bit);
        const unsigned tb = cb | (1u << bit);
        int cntA = 0, cntB = 0;
#pragma unroll
        for (int j = 0; j < 32; ++j) cntA += __popcll(__ballot(ua[j] >= ta));
#pragma unroll
        for (int j = 0; j < 32; ++j) cntB += __popcll(__ballot(ub[j] >= tb));
        if (cntA >= K_) ca = ta;
        if (cntB >= K_) cb = tb;
    }

    // Exact sum of values strictly above cand + tie adjustment at cand.
    float sa = 0.f, sb = 0.f;
    int ga = 0, gb = 0;
#pragma unroll
    for (int j = 0; j < 32; ++j) {
        const unsigned va = ua[j], vb = ub[j];
        const float fa = __uint_as_float((va & 0x80000000u) ? (va ^ 0x80000000u) : ~va);
        const float fb = __uint_as_float((vb & 0x80000000u) ? (vb ^ 0x80000000u) : ~vb);
        const bool pa = va > ca, pb = vb > cb;
        sa += pa ? fa : 0.f;
        sb += pb ? fb : 0.f;
        ga += __popcll(__ballot(pa));
        gb += __popcll(__ballot(pb));
    }
#pragma unroll
    for (int o = 32; o; o >>= 1) {
        sa += __shfl_xor(sa, o, 64);
        sb += __shfl_xor(sb, o, 64);
    }

    if (lane == 0) {
        const float tva = __uint_as_float((ca & 0x80000000u) ? (ca ^ 0x80000000u) : ~ca);
        const float tvb = __uint_as_float((cb & 0x80000000u) ? (cb ^ 0x80000000u) : ~cb);
        const float qba = ws[WS_QB + b * N_ + n0];
        const float qbb = ws[WS_QB + b * N_ + n0 + 1];
        const float colsum = sa + (float)(K_ - ga) * tva + (float)K_ * qba
                           + sb + (float)(K_ - gb) * tvb + (float)K_ * qbb;
        atomicAdd(ws + WS_ACC, colsum);
    }

    // Last block writes the final mean (divide by B*N*K = 2^20, exact scale).
    __syncthreads();
    if (tid == 0) {
        __threadfence();
        const int done = atomicAdd((int*)ws + WS_CNT, 1);
        if (done == (N_ / 8) * B_ - 1) {
            __threadfence();
            const float acc = atomicAdd(ws + WS_ACC, 0.f);  // device-coherent read
            out[0] = acc * (1.0f / 1048576.0f);
        }
    }
}

// ---------------------------------------------------------------------------
extern "C" void kernel_launch(void* const* d_in, const int* in_sizes, int n_in,
                              void* d_out, int out_size, void* d_ws, size_t ws_size,
                              hipStream_t stream)
{
    (void)in_sizes; (void)n_in; (void)out_size; (void)ws_size;
    const float* outputs = (const float*)d_in[0];  // (B,N,9) fp32
    const float* targets = (const float*)d_in[1];  // (B,M,9) fp32
    float* ws  = (float*)d_ws;
    float* out = (float*)d_out;

    stats_pinv_kernel<<<B_, 256, 0, stream>>>(targets, ws);
    prep_kernel<<<(B_ * (M_ + N_)) / 256, 256, 0, stream>>>(outputs, targets, ws);
    topk_kernel<<<dim3(N_ / 8, B_), 256, 0, stream>>>(outputs, ws, out);
}